// Round 15
// baseline (366.460 us; speedup 1.0000x reference)
//
#include <hip/hip_runtime.h>

// Equalization: images [64, 512, 512, 3] int32 in [0,255].
// Per (batch, channel): histogram (256 bins == value counts since bin==value
// for v in [0,255] under tf.histogram_fixed_width), cumsum LUT, gather by
// pixel value. Output dtype = int32 (reference returns .astype(img.dtype);
// harness reads d_out as np.int32 — confirmed by R11 failure signature).

#define NB   64
#define HW   262144                      // 512*512
#define CH   3
#define EPI  (HW * CH)                   // 786432 elements per image
#define EPB  4096                        // elements per block
#define BPI  (EPI / EPB)                 // 192 blocks per image
#define NHIST (NB * CH)                  // 192 histograms
#define NBINS 256

typedef int vint4 __attribute__((ext_vector_type(4)));  // native vec for nontemporal builtin

// ---------------- kernel 1: per-(image,channel) histograms ----------------
__global__ __launch_bounds__(256) void eq_hist(const int* __restrict__ in,
                                               int* __restrict__ ghist) {
    __shared__ int h[CH * NBINS];
    const int t = threadIdx.x;
    for (int r = t; r < CH * NBINS; r += 256) h[r] = 0;
    __syncthreads();

    const int img   = blockIdx.x / BPI;
    const int chunk = blockIdx.x % BPI;
    const int base  = img * EPI + chunk * EPB;     // fits in int (< 2^26)
    const int4* p = (const int4*)(in + base);

    // channel of element (base + 4*t): EPI%3==0, so phase depends on chunk,t
    int c0 = (base + t * 4) % 3;
    const int c1 = (c0 + 1 == 3) ? 0 : c0 + 1;
    const int c2 = (c1 + 1 == 3) ? 0 : c1 + 1;
    // stepping idx4 by 256: 1024 elements -> phase advance 1024%3 == 1
#pragma unroll
    for (int k = 0; k < 4; ++k) {
        const int idx4 = t + k * 256;
        int4 x = p[idx4];
        const int ca = (k == 0) ? c0 : (k == 1) ? c1 : (k == 2) ? c2 : c0;
        const int cb = (ca + 1 == 3) ? 0 : ca + 1;
        const int cc = (cb + 1 == 3) ? 0 : cb + 1;
        atomicAdd(&h[ca * NBINS + min(max(x.x, 0), 255)], 1);
        atomicAdd(&h[cb * NBINS + min(max(x.y, 0), 255)], 1);
        atomicAdd(&h[cc * NBINS + min(max(x.z, 0), 255)], 1);
        atomicAdd(&h[ca * NBINS + min(max(x.w, 0), 255)], 1);
    }
    __syncthreads();

    int* gh = ghist + img * (CH * NBINS);          // layout (img*3+c)*256+v
    for (int r = t; r < CH * NBINS; r += 256) {
        int v = h[r];
        if (v) atomicAdd(&gh[r], v);
    }
}

// ---------------- kernel 2: build LUTs (one block per histogram) ----------
__global__ __launch_bounds__(256) void eq_lut(const int* __restrict__ ghist,
                                              int* __restrict__ glut) {
    __shared__ int hv[NBINS];
    __shared__ int cs[NBINS];
    __shared__ int red[NBINS];
    const int v   = threadIdx.x;
    const int hid = blockIdx.x;

    int hval = ghist[hid * NBINS + v];
    hv[v]  = hval;
    cs[v]  = hval;
    red[v] = (hval > 0) ? v : -1;
    __syncthreads();

    // max-reduce: index of last nonzero bin
    for (int o = 128; o >= 1; o >>= 1) {
        if (v < o) red[v] = max(red[v], red[v + o]);
        __syncthreads();
    }
    // inclusive scan (Hillis-Steele)
    for (int o = 1; o < NBINS; o <<= 1) {
        int add = (v >= o) ? cs[v - o] : 0;
        __syncthreads();
        cs[v] += add;
        __syncthreads();
    }

    const int last     = red[0];
    const int last_val = hv[max(last, 0)];
    const int total    = cs[NBINS - 1];
    const int step     = (total - last_val) / (NBINS - 1);

    int lutv;
    if (step == 0) {
        lutv = v;                          // where(step==0, img, eq) -> identity
    } else {
        int c = (v == 0) ? 0 : cs[v - 1];  // shifted cumsum; v==0 -> 0 exactly
        lutv = min((c + step / 2) / step, 255);
    }
    glut[hid * NBINS + v] = lutv;
}

// ---------------- kernel 3: apply LUTs ------------------------------------
__global__ __launch_bounds__(256) void eq_apply(const int* __restrict__ in,
                                                const int* __restrict__ glut,
                                                int* __restrict__ out) {
    __shared__ int l[CH * NBINS];
    const int t = threadIdx.x;
    const int img   = blockIdx.x / BPI;
    const int chunk = blockIdx.x % BPI;

    const int* gl = glut + img * (CH * NBINS);
    for (int r = t; r < CH * NBINS; r += 256) l[r] = gl[r];
    __syncthreads();

    const int base = img * EPI + chunk * EPB;
    const int4* p = (const int4*)(in + base);
    vint4* q = (vint4*)(out + base);

    int c0 = (base + t * 4) % 3;
    const int c1 = (c0 + 1 == 3) ? 0 : c0 + 1;
    const int c2 = (c1 + 1 == 3) ? 0 : c1 + 1;
#pragma unroll
    for (int k = 0; k < 4; ++k) {
        const int idx4 = t + k * 256;
        int4 x = p[idx4];
        const int ca = (k == 0) ? c0 : (k == 1) ? c1 : (k == 2) ? c2 : c0;
        const int cb = (ca + 1 == 3) ? 0 : ca + 1;
        const int cc = (cb + 1 == 3) ? 0 : cb + 1;
        vint4 y;
        y.x = l[ca * NBINS + min(max(x.x, 0), 255)];
        y.y = l[cb * NBINS + min(max(x.y, 0), 255)];
        y.z = l[cc * NBINS + min(max(x.z, 0), 255)];
        y.w = l[ca * NBINS + min(max(x.w, 0), 255)];
        // Output is written once and never re-read: nontemporal store keeps
        // the input resident in L3 for the duration of this kernel.
        __builtin_nontemporal_store(y, &q[idx4]);
    }
}

extern "C" void kernel_launch(void* const* d_in, const int* in_sizes, int n_in,
                              void* d_out, int out_size, void* d_ws, size_t ws_size,
                              hipStream_t stream) {
    const int* in = (const int*)d_in[0];
    int* out = (int*)d_out;

    int* ghist = (int*)d_ws;
    int* glut  = (int*)((char*)d_ws + NHIST * NBINS * sizeof(int));

    // d_ws is poisoned 0xAA before every launch — zero the histograms.
    (void)hipMemsetAsync(ghist, 0, NHIST * NBINS * sizeof(int), stream);

    eq_hist <<<NB * BPI, 256, 0, stream>>>(in, ghist);
    eq_lut  <<<NHIST,    256, 0, stream>>>(ghist, glut);
    eq_apply<<<NB * BPI, 256, 0, stream>>>(in, glut, out);
}